// Round 3
// baseline (2907.866 us; speedup 1.0000x reference)
//
#include <hip/hip_runtime.h>

// Problem constants (B=64, S=512, D=512, K=4096)
#define N_ROWS 32768          // B*S
#define DIM    512
#define KCODES 4096
#define KHALF  2048           // codes per K-split block
#define Q_ELEMS (N_ROWS * DIM)      // 16777216
#define LOSS_OFF Q_ELEMS            // 1 float
#define IDX_OFF (Q_ELEMS + 1)       // 32768 floats

// ---------------- Kernel 1a: codebook norms ||c_k||^2 (fp32) ----------------
__global__ void k_cnorm(const float* __restrict__ cb, float* __restrict__ cnorm) {
    int wave = (blockIdx.x * blockDim.x + threadIdx.x) >> 6;
    int lane = threadIdx.x & 63;
    if (wave >= KCODES) return;
    const float4* row = (const float4*)(cb + (size_t)wave * DIM);
    float4 v1 = row[lane];
    float4 v2 = row[lane + 64];
    float s = v1.x*v1.x + v1.y*v1.y + v1.z*v1.z + v1.w*v1.w
            + v2.x*v2.x + v2.y*v2.y + v2.z*v2.z + v2.w*v2.w;
    #pragma unroll
    for (int m = 32; m >= 1; m >>= 1) s += __shfl_xor(s, m);
    if (lane == 0) cnorm[wave] = s;
}

// ---------------- Kernel 1b: input row norms ||x_n||^2 (fp32) ----------------
__global__ void k_xnorm(const float* __restrict__ x, float* __restrict__ xnorm) {
    int wave = (blockIdx.x * blockDim.x + threadIdx.x) >> 6;
    int lane = threadIdx.x & 63;
    if (wave >= N_ROWS) return;
    const float4* row = (const float4*)(x + (size_t)wave * DIM);
    float4 v1 = row[lane];
    float4 v2 = row[lane + 64];
    float s = v1.x*v1.x + v1.y*v1.y + v1.z*v1.z + v1.w*v1.w
            + v2.x*v2.x + v2.y*v2.y + v2.z*v2.z + v2.w*v2.w;
    #pragma unroll
    for (int m = 32; m >= 1; m >>= 1) s += __shfl_xor(s, m);
    if (lane == 0) xnorm[wave] = s;
}

// ---------------- Kernel 2: fp32-formula distance + partial argmin ----------------
// dist32(n,k) = fl32( fl32(xnorm + cnorm[k]) - fl32(2 * dot(n,k)) ), dot as a
// sequential-d fp32 fma chain — bit-identical per (n,k) to the round-2 pass.
// K-split: blockIdx.y selects codes [half*2048, half*2048+2048); partial
// (best,idx) per row written to workspace, merged in k_gather.
#define BM 64
#define BN 128
#define BD 32
#define NCHUNK ((KHALF / BN) * (DIM / BD))   // 16 kc * 16 dc = 256

__global__ __launch_bounds__(256, 4)
void k_argmin(const float* __restrict__ x, const float* __restrict__ cb,
              const float* __restrict__ cnorm, const float* __restrict__ xnorm,
              float* __restrict__ bestv, int* __restrict__ bestk) {
    __shared__ float xs[BM][BD + 4];   // stride 36 floats (16B-aligned, bank-spread)
    __shared__ float cs[BD][BN];       // transposed: cs[d][k]

    const int tid = threadIdx.x;
    const int ty = tid >> 4;           // 0..15
    const int tx = tid & 15;           // 0..15
    const int r0 = blockIdx.x * BM;
    const int kbase = blockIdx.y * KHALF;

    // staging coordinates (fixed per thread)
    const int xrow1 = tid >> 3,        xdq1 = tid & 7;         // f = tid
    const int xrow2 = (tid + 256) >> 3, xdq2 = tid & 7;        // f = tid+256
    const int ck = tid & 127;
    const int cdq0 = (tid >> 7);                                // 0..1

    float xn[4];
    #pragma unroll
    for (int i = 0; i < 4; ++i) xn[i] = xnorm[r0 + ty * 4 + i];

    float best[4];
    int   bidx[4];
    #pragma unroll
    for (int i = 0; i < 4; ++i) { best[i] = 3.4e38f; bidx[i] = kbase; }

    float acc[4][8];

    // prefetch registers
    float4 xr0, xr1, cr[4];

    // ---- load chunk 0 ----
    {
        const int kc = 0, dc = 0;
        xr0 = *(const float4*)(x + (size_t)(r0 + xrow1) * DIM + dc + xdq1 * 4);
        xr1 = *(const float4*)(x + (size_t)(r0 + xrow2) * DIM + dc + xdq2 * 4);
        #pragma unroll
        for (int it2 = 0; it2 < 4; ++it2) {
            int dq = cdq0 + it2 * 2;
            cr[it2] = *(const float4*)(cb + (size_t)(kbase + kc * BN + ck) * DIM + dc + dq * 4);
        }
    }

    for (int it = 0; it < NCHUNK; ++it) {
        const int kc = it >> 4;            // 0..15
        // (dc = (it & 15) * BD)

        __syncthreads();   // previous chunk's readers done
        // write prefetched regs -> LDS
        *(float4*)&xs[xrow1][xdq1 * 4] = xr0;
        *(float4*)&xs[xrow2][xdq2 * 4] = xr1;
        #pragma unroll
        for (int it2 = 0; it2 < 4; ++it2) {
            int dq = cdq0 + it2 * 2;
            cs[dq * 4 + 0][ck] = cr[it2].x;
            cs[dq * 4 + 1][ck] = cr[it2].y;
            cs[dq * 4 + 2][ck] = cr[it2].z;
            cs[dq * 4 + 3][ck] = cr[it2].w;
        }
        __syncthreads();   // tile ready

        // issue next chunk's loads (hide under compute)
        if (it + 1 < NCHUNK) {
            const int nkc = (it + 1) >> 4;
            const int ndc = ((it + 1) & 15) * BD;
            xr0 = *(const float4*)(x + (size_t)(r0 + xrow1) * DIM + ndc + xdq1 * 4);
            xr1 = *(const float4*)(x + (size_t)(r0 + xrow2) * DIM + ndc + xdq2 * 4);
            #pragma unroll
            for (int it2 = 0; it2 < 4; ++it2) {
                int dq = cdq0 + it2 * 2;
                cr[it2] = *(const float4*)(cb + (size_t)(kbase + nkc * BN + ck) * DIM + ndc + dq * 4);
            }
        }

        if ((it & 15) == 0) {
            #pragma unroll
            for (int i = 0; i < 4; ++i)
                #pragma unroll
                for (int j = 0; j < 8; ++j) acc[i][j] = 0.f;
        }

        // compute: 32 d-steps, d ascending (chain order identical to round 2)
        #pragma unroll
        for (int d4 = 0; d4 < 8; ++d4) {
            float xa[4][4];
            #pragma unroll
            for (int i = 0; i < 4; ++i)
                *(float4*)&xa[i][0] = *(const float4*)&xs[ty * 4 + i][d4 * 4];
            #pragma unroll
            for (int dd = 0; dd < 4; ++dd) {
                int d = d4 * 4 + dd;
                float4 b0 = *(const float4*)&cs[d][tx * 4];
                float4 b1 = *(const float4*)&cs[d][64 + tx * 4];
                #pragma unroll
                for (int i = 0; i < 4; ++i) {
                    float a = xa[i][dd];
                    acc[i][0] = fmaf(a, b0.x, acc[i][0]);
                    acc[i][1] = fmaf(a, b0.y, acc[i][1]);
                    acc[i][2] = fmaf(a, b0.z, acc[i][2]);
                    acc[i][3] = fmaf(a, b0.w, acc[i][3]);
                    acc[i][4] = fmaf(a, b1.x, acc[i][4]);
                    acc[i][5] = fmaf(a, b1.y, acc[i][5]);
                    acc[i][6] = fmaf(a, b1.z, acc[i][6]);
                    acc[i][7] = fmaf(a, b1.w, acc[i][7]);
                }
            }
        }

        // end of a kc block: scores + running argmin, k ascending per thread
        if ((it & 15) == 15) {
            #pragma unroll
            for (int half = 0; half < 2; ++half) {
                #pragma unroll
                for (int j = 0; j < 4; ++j) {
                    int k = kbase + kc * BN + half * 64 + tx * 4 + j;
                    float cn = cnorm[k];
                    #pragma unroll
                    for (int i = 0; i < 4; ++i) {
                        float t1 = xn[i] + cn;                  // fl32(xn + cn)
                        float tw = 2.0f * acc[i][half * 4 + j]; // exact x2
                        float s  = t1 - tw;                     // fl32(t1 - tw)
                        if (s < best[i]) { best[i] = s; bidx[i] = k; }
                    }
                }
            }
        }
    }

    // cross-tx reduce: strictly-smaller wins; tie -> lower index
    #pragma unroll
    for (int i = 0; i < 4; ++i) {
        float b = best[i];
        int   ix = bidx[i];
        #pragma unroll
        for (int m = 1; m <= 8; m <<= 1) {
            float ob = __shfl_xor(b, m);
            int   oi = __shfl_xor(ix, m);
            if (ob < b || (ob == b && oi < ix)) { b = ob; ix = oi; }
        }
        if (tx == 0) {
            int row = r0 + ty * 4 + i;
            bestv[(size_t)blockIdx.y * N_ROWS + row] = b;
            bestk[(size_t)blockIdx.y * N_ROWS + row] = ix;
        }
    }
}

// ---------------- Kernel 3: merge halves + gather + loss partials ----------------
__global__ void k_gather(const float* __restrict__ x, const float* __restrict__ cb,
                         const float* __restrict__ bestv, const int* __restrict__ bestk,
                         float* __restrict__ qout, float* __restrict__ idx_out,
                         float* __restrict__ partial) {
    int row  = blockIdx.x * 4 + (threadIdx.x >> 6);
    int lane = threadIdx.x & 63;
    // merge: half-0 indices are always lower, so tie -> half 0
    float v0 = bestv[row], v1 = bestv[N_ROWS + row];
    int   k  = (v1 < v0) ? bestk[N_ROWS + row] : bestk[row];
    if (lane == 0) idx_out[row] = (float)k;
    const float4* crow = (const float4*)(cb + (size_t)k * DIM);
    const float4* xrow = (const float4*)(x + (size_t)row * DIM);
    float4* qrow = (float4*)(qout + (size_t)row * DIM);
    float s = 0.f;
    #pragma unroll
    for (int it = 0; it < 2; ++it) {
        int d4 = lane + it * 64;
        float4 q = crow[d4];
        float4 xi = xrow[d4];
        qrow[d4] = q;
        float dx = q.x - xi.x; s += dx * dx;
        dx = q.y - xi.y; s += dx * dx;
        dx = q.z - xi.z; s += dx * dx;
        dx = q.w - xi.w; s += dx * dx;
    }
    #pragma unroll
    for (int m = 32; m >= 1; m >>= 1) s += __shfl_xor(s, m);
    __shared__ float ws4[4];
    if (lane == 0) ws4[threadIdx.x >> 6] = s;
    __syncthreads();
    if (threadIdx.x == 0)
        partial[blockIdx.x] = (ws4[0] + ws4[1]) + (ws4[2] + ws4[3]);
}

// ---------------- Kernel 4: deterministic final loss reduce ----------------
__global__ void k_loss(const float* __restrict__ partial, float* __restrict__ out_loss) {
    int t = threadIdx.x;   // 256 threads, 8192 partials
    double s = 0.0;
    #pragma unroll 4
    for (int i = 0; i < 32; ++i) s += (double)partial[t * 32 + i];
    #pragma unroll
    for (int m = 32; m >= 1; m >>= 1) s += __shfl_xor(s, m);
    __shared__ double sd[4];
    if ((t & 63) == 0) sd[t >> 6] = s;
    __syncthreads();
    if (t == 0) {
        double tot = (sd[0] + sd[1]) + (sd[2] + sd[3]);
        out_loss[0] = (float)(1.25 * tot / (double)Q_ELEMS);
    }
}

extern "C" void kernel_launch(void* const* d_in, const int* in_sizes, int n_in,
                              void* d_out, int out_size, void* d_ws, size_t ws_size,
                              hipStream_t stream) {
    const float* x  = (const float*)d_in[0];   // [32768, 512]
    const float* cb = (const float*)d_in[1];   // [4096, 512]
    float* out = (float*)d_out;

    char* ws = (char*)d_ws;
    float* cnorm = (float*)ws;                      ws += (size_t)KCODES * 4;
    float* xnorm = (float*)ws;                      ws += (size_t)N_ROWS * 4;
    float* bestv = (float*)ws;                      ws += (size_t)2 * N_ROWS * 4;
    int*   bestk = (int*)ws;                        ws += (size_t)2 * N_ROWS * 4;
    float* part  = (float*)ws;

    k_cnorm<<<KCODES / 4, 256, 0, stream>>>(cb, cnorm);
    k_xnorm<<<N_ROWS / 4, 256, 0, stream>>>(x, xnorm);
    dim3 agrid(N_ROWS / BM, 2);
    k_argmin<<<agrid, 256, 0, stream>>>(x, cb, cnorm, xnorm, bestv, bestk);
    k_gather<<<N_ROWS / 4, 256, 0, stream>>>(x, cb, bestv, bestk, out, out + IDX_OFF, part);
    k_loss<<<1, 256, 0, stream>>>(part, out + LOSS_OFF);
}

// Round 4
// 1714.716 us; speedup vs baseline: 1.6958x; 1.6958x over previous
//
#include <hip/hip_runtime.h>

// Problem constants (B=64, S=512, D=512, K=4096)
#define N_ROWS 32768          // B*S
#define DIM    512
#define KCODES 4096
#define KHALF  2048           // codes per K-split block
#define Q_ELEMS (N_ROWS * DIM)      // 16777216
#define LOSS_OFF Q_ELEMS            // 1 float
#define IDX_OFF (Q_ELEMS + 1)       // 32768 floats

// ---------------- Kernel 1a: codebook norms ||c_k||^2 (fp32) ----------------
__global__ void k_cnorm(const float* __restrict__ cb, float* __restrict__ cnorm) {
    int wave = (blockIdx.x * blockDim.x + threadIdx.x) >> 6;
    int lane = threadIdx.x & 63;
    if (wave >= KCODES) return;
    const float4* row = (const float4*)(cb + (size_t)wave * DIM);
    float4 v1 = row[lane];
    float4 v2 = row[lane + 64];
    float s = v1.x*v1.x + v1.y*v1.y + v1.z*v1.z + v1.w*v1.w
            + v2.x*v2.x + v2.y*v2.y + v2.z*v2.z + v2.w*v2.w;
    #pragma unroll
    for (int m = 32; m >= 1; m >>= 1) s += __shfl_xor(s, m);
    if (lane == 0) cnorm[wave] = s;
}

// ---------------- Kernel 1b: input row norms ||x_n||^2 (fp32) ----------------
__global__ void k_xnorm(const float* __restrict__ x, float* __restrict__ xnorm) {
    int wave = (blockIdx.x * blockDim.x + threadIdx.x) >> 6;
    int lane = threadIdx.x & 63;
    if (wave >= N_ROWS) return;
    const float4* row = (const float4*)(x + (size_t)wave * DIM);
    float4 v1 = row[lane];
    float4 v2 = row[lane + 64];
    float s = v1.x*v1.x + v1.y*v1.y + v1.z*v1.z + v1.w*v1.w
            + v2.x*v2.x + v2.y*v2.y + v2.z*v2.z + v2.w*v2.w;
    #pragma unroll
    for (int m = 32; m >= 1; m >>= 1) s += __shfl_xor(s, m);
    if (lane == 0) xnorm[wave] = s;
}

// ---------------- Kernel 2: fp32-formula distance + partial argmin ----------------
// dist32(n,k) = fl32( fl32(xnorm + cnorm[k]) - fl32(2 * dot(n,k)) ), dot as a
// sequential-d fp32 fma chain — bit-identical per (n,k) to the passing rounds.
// K-split via blockIdx.y (codes [y*2048, y*2048+2048)); merged in k_gather.
// NOTE: no register prefetch, no launch-bounds min-wave hint — round 3 showed
// those trigger accumulator spill (WRITE_SIZE 272KB -> 6.5GB). Keep VGPR <= 64.
#define BM 64
#define BN 128
#define BD 32

__global__ __launch_bounds__(256)
void k_argmin(const float* __restrict__ x, const float* __restrict__ cb,
              const float* __restrict__ cnorm, const float* __restrict__ xnorm,
              float* __restrict__ bestv, int* __restrict__ bestk) {
    __shared__ float xs[BM][BD + 4];   // stride 36 floats (16B-aligned; A-reads 2-way banked = free)
    __shared__ float cs[BD][BN];       // transposed: cs[d][k]

    const int tid = threadIdx.x;
    const int ty = tid >> 4;           // 0..15
    const int tx = tid & 15;           // 0..15
    const int r0 = blockIdx.x * BM;
    const int kbase = blockIdx.y * KHALF;

    float xn[4];
    #pragma unroll
    for (int i = 0; i < 4; ++i) xn[i] = xnorm[r0 + ty * 4 + i];

    float best[4];
    int   bidx[4];
    #pragma unroll
    for (int i = 0; i < 4; ++i) { best[i] = 3.4e38f; bidx[i] = kbase; }

    for (int kc = 0; kc < KHALF; kc += BN) {
        float acc[4][8];
        #pragma unroll
        for (int i = 0; i < 4; ++i)
            #pragma unroll
            for (int j = 0; j < 8; ++j) acc[i][j] = 0.f;

        for (int dc = 0; dc < DIM; dc += BD) {
            // stage x tile: 64 rows x 32 d
            #pragma unroll
            for (int it = 0; it < 2; ++it) {
                int f = tid + it * 256;
                int row = f >> 3;
                int dq  = f & 7;
                float4 v = *(const float4*)(x + (size_t)(r0 + row) * DIM + dc + dq * 4);
                *(float4*)&xs[row][dq * 4] = v;
            }
            // stage code tile transposed: 128 codes x 32 d
            #pragma unroll
            for (int it = 0; it < 4; ++it) {
                int k  = tid & 127;
                int dq = (tid >> 7) + it * 2;
                float4 v = *(const float4*)(cb + (size_t)(kbase + kc + k) * DIM + dc + dq * 4);
                cs[dq * 4 + 0][k] = v.x;
                cs[dq * 4 + 1][k] = v.y;
                cs[dq * 4 + 2][k] = v.z;
                cs[dq * 4 + 3][k] = v.w;
            }
            __syncthreads();

            // compute: 32 d-steps, d ascending (chain order = reference order)
            #pragma unroll
            for (int d4 = 0; d4 < 8; ++d4) {
                float xa[4][4];
                #pragma unroll
                for (int i = 0; i < 4; ++i)
                    *(float4*)&xa[i][0] = *(const float4*)&xs[ty * 4 + i][d4 * 4];
                #pragma unroll
                for (int dd = 0; dd < 4; ++dd) {
                    int d = d4 * 4 + dd;
                    float4 b0 = *(const float4*)&cs[d][tx * 4];
                    float4 b1 = *(const float4*)&cs[d][64 + tx * 4];
                    #pragma unroll
                    for (int i = 0; i < 4; ++i) {
                        float a = xa[i][dd];
                        acc[i][0] = fmaf(a, b0.x, acc[i][0]);
                        acc[i][1] = fmaf(a, b0.y, acc[i][1]);
                        acc[i][2] = fmaf(a, b0.z, acc[i][2]);
                        acc[i][3] = fmaf(a, b0.w, acc[i][3]);
                        acc[i][4] = fmaf(a, b1.x, acc[i][4]);
                        acc[i][5] = fmaf(a, b1.y, acc[i][5]);
                        acc[i][6] = fmaf(a, b1.z, acc[i][6]);
                        acc[i][7] = fmaf(a, b1.w, acc[i][7]);
                    }
                }
            }
            __syncthreads();
        }

        // scores in reference fp32 order; k ascending per thread
        #pragma unroll
        for (int half = 0; half < 2; ++half) {
            #pragma unroll
            for (int j = 0; j < 4; ++j) {
                int k = kbase + kc + half * 64 + tx * 4 + j;
                float cn = cnorm[k];
                #pragma unroll
                for (int i = 0; i < 4; ++i) {
                    float t1 = xn[i] + cn;                  // fl32(xn + cn)
                    float tw = 2.0f * acc[i][half * 4 + j]; // exact x2
                    float s  = t1 - tw;                     // fl32(t1 - tw)
                    if (s < best[i]) { best[i] = s; bidx[i] = k; }
                }
            }
        }
    }

    // cross-tx reduce: strictly-smaller wins; tie -> lower index
    #pragma unroll
    for (int i = 0; i < 4; ++i) {
        float b = best[i];
        int   ix = bidx[i];
        #pragma unroll
        for (int m = 1; m <= 8; m <<= 1) {
            float ob = __shfl_xor(b, m);
            int   oi = __shfl_xor(ix, m);
            if (ob < b || (ob == b && oi < ix)) { b = ob; ix = oi; }
        }
        if (tx == 0) {
            int row = r0 + ty * 4 + i;
            bestv[(size_t)blockIdx.y * N_ROWS + row] = b;
            bestk[(size_t)blockIdx.y * N_ROWS + row] = ix;
        }
    }
}

// ---------------- Kernel 3: merge halves + gather + loss partials ----------------
__global__ void k_gather(const float* __restrict__ x, const float* __restrict__ cb,
                         const float* __restrict__ bestv, const int* __restrict__ bestk,
                         float* __restrict__ qout, float* __restrict__ idx_out,
                         float* __restrict__ partial) {
    int row  = blockIdx.x * 4 + (threadIdx.x >> 6);
    int lane = threadIdx.x & 63;
    // merge: half-0 indices are always lower, so tie -> half 0
    float v0 = bestv[row], v1 = bestv[N_ROWS + row];
    int   k  = (v1 < v0) ? bestk[N_ROWS + row] : bestk[row];
    if (lane == 0) idx_out[row] = (float)k;
    const float4* crow = (const float4*)(cb + (size_t)k * DIM);
    const float4* xrow = (const float4*)(x + (size_t)row * DIM);
    float4* qrow = (float4*)(qout + (size_t)row * DIM);
    float s = 0.f;
    #pragma unroll
    for (int it = 0; it < 2; ++it) {
        int d4 = lane + it * 64;
        float4 q = crow[d4];
        float4 xi = xrow[d4];
        qrow[d4] = q;
        float dx = q.x - xi.x; s += dx * dx;
        dx = q.y - xi.y; s += dx * dx;
        dx = q.z - xi.z; s += dx * dx;
        dx = q.w - xi.w; s += dx * dx;
    }
    #pragma unroll
    for (int m = 32; m >= 1; m >>= 1) s += __shfl_xor(s, m);
    __shared__ float ws4[4];
    if (lane == 0) ws4[threadIdx.x >> 6] = s;
    __syncthreads();
    if (threadIdx.x == 0)
        partial[blockIdx.x] = (ws4[0] + ws4[1]) + (ws4[2] + ws4[3]);
}

// ---------------- Kernel 4: deterministic final loss reduce ----------------
__global__ void k_loss(const float* __restrict__ partial, float* __restrict__ out_loss) {
    int t = threadIdx.x;   // 256 threads, 8192 partials
    double s = 0.0;
    #pragma unroll 4
    for (int i = 0; i < 32; ++i) s += (double)partial[t * 32 + i];
    #pragma unroll
    for (int m = 32; m >= 1; m >>= 1) s += __shfl_xor(s, m);
    __shared__ double sd[4];
    if ((t & 63) == 0) sd[t >> 6] = s;
    __syncthreads();
    if (t == 0) {
        double tot = (sd[0] + sd[1]) + (sd[2] + sd[3]);
        out_loss[0] = (float)(1.25 * tot / (double)Q_ELEMS);
    }
}

extern "C" void kernel_launch(void* const* d_in, const int* in_sizes, int n_in,
                              void* d_out, int out_size, void* d_ws, size_t ws_size,
                              hipStream_t stream) {
    const float* x  = (const float*)d_in[0];   // [32768, 512]
    const float* cb = (const float*)d_in[1];   // [4096, 512]
    float* out = (float*)d_out;

    char* ws = (char*)d_ws;
    float* cnorm = (float*)ws;                      ws += (size_t)KCODES * 4;
    float* xnorm = (float*)ws;                      ws += (size_t)N_ROWS * 4;
    float* bestv = (float*)ws;                      ws += (size_t)2 * N_ROWS * 4;
    int*   bestk = (int*)ws;                        ws += (size_t)2 * N_ROWS * 4;
    float* part  = (float*)ws;

    k_cnorm<<<KCODES / 4, 256, 0, stream>>>(cb, cnorm);
    k_xnorm<<<N_ROWS / 4, 256, 0, stream>>>(x, xnorm);
    dim3 agrid(N_ROWS / BM, 2);
    k_argmin<<<agrid, 256, 0, stream>>>(x, cb, cnorm, xnorm, bestv, bestk);
    k_gather<<<N_ROWS / 4, 256, 0, stream>>>(x, cb, bestv, bestk, out, out + IDX_OFF, part);
    k_loss<<<1, 256, 0, stream>>>(part, out + LOSS_OFF);
}